// Round 1
// baseline (270.816 us; speedup 1.0000x reference)
//
#include <hip/hip_runtime.h>
#include <math.h>

// Soft-DTW shape loss (DILATE, alpha=1, gamma=0.01) on B=64, N=512, F=1.
// n = N-1 = 511. One block per batch; thread t owns row i=t of the
// anti-diagonal wavefront. 1021 sequential diagonals, 1 barrier each.

#define NSEQ 511
#define NP1  512
#define GAMMA_F 0.01f
#define INF_F 1000000000.0f

__global__ __launch_bounds__(512)
void sdtw_kernel(const float* __restrict__ input,
                 const float* __restrict__ target,
                 float* __restrict__ out) {
    const int b = blockIdx.x;
    const int t = threadIdx.x;           // i index, 0..511 (n=511)

    __shared__ float dxs[NSEQ];          // dx[j] = input[j+1]-input[j]
    __shared__ float buf[3][NP1];        // rotating diagonals R(d-2), R(d-1), R(d)

    const float* inp = input  + b * 512;  // (B, N, 1) contiguous
    const float* tgt = target + b * 512;

    if (t < NSEQ) dxs[t] = inp[t + 1] - inp[t];
    float dy_t = 0.0f;
    if (t >= 1) dy_t = tgt[t] - tgt[t - 1];   // dy[t-1]

    // diag d=0: only cell (0,0)=0; diag d=1: all INF
    buf[0][t] = (t == 0) ? 0.0f : INF_F;
    buf[1][t] = INF_F;
    __syncthreads();

    int i2 = 0, i1 = 1, in_ = 2;
    const float inv_g = 1.0f / GAMMA_F;

    for (int d = 2; d <= 2 * NSEQ; ++d) {
        float nv = INF_F;
        const int j = d - t;
        if (t >= 1 && j >= 1 && j <= NSEQ) {
            // softmin_gamma(R[i-1,j-1], R[i-1,j], R[i,j-1])
            const float a = buf[i2][t - 1];   // R[i-1, j-1]  (diag d-2)
            const float c = buf[i1][t - 1];   // R[i-1, j]    (diag d-1)
            const float e = buf[i1][t];       // R[i,   j-1]  (diag d-1)
            const float m = fminf(fminf(a, c), e);
            const float s = __expf((m - a) * inv_g)
                          + __expf((m - c) * inv_g)
                          + __expf((m - e) * inv_g);
            const float smin = m - GAMMA_F * __logf(s);
            const float diff = dy_t - dxs[j - 1];
            nv = fmaf(diff, diff, smin);
        }
        buf[in_][t] = nv;
        __syncthreads();
        const int tmp = i2; i2 = i1; i1 = in_; in_ = tmp;
    }

    // after last rotation, i1 holds diag d=2n; R[n,n] is at index n
    if (t == NSEQ) {
        atomicAdd(out, buf[i1][NSEQ] * (1.0f / 64.0f));
    }
}

extern "C" void kernel_launch(void* const* d_in, const int* in_sizes, int n_in,
                              void* d_out, int out_size, void* d_ws, size_t ws_size,
                              hipStream_t stream) {
    const float* input  = (const float*)d_in[0];
    const float* target = (const float*)d_in[1];
    float* out = (float*)d_out;

    hipMemsetAsync(out, 0, sizeof(float), stream);
    sdtw_kernel<<<64, 512, 0, stream>>>(input, target, out);
}

// Round 2
// 231.942 us; speedup vs baseline: 1.1676x; 1.1676x over previous
//
#include <hip/hip_runtime.h>
#include <math.h>

// Soft-DTW (DILATE shape loss, alpha=1, gamma=0.01), B=64, N=512, F=1, n=511.
// One block per batch. 256 threads = 4 waves; thread t owns rows {2t, 2t+1}
// of the (n+1)x(n+1) DP matrix (row 0 = boundary row). Anti-diagonal
// wavefront kept in registers; lane->lane dependency via __shfl_up; wave->wave
// dependency via an LDS mailbox indexed by diagonal, pipelined in chunks of
// KCH diagonals with acquire/release LDS flags. NO __syncthreads in the loop.

#define INF_F 1000000000.0f
#define KCH 16
#define NCHUNK 64      // 64*16 = 1024 >= 1021 diagonals (d = 2..1022)
#define DMAX 1022

__device__ __forceinline__ float fast_exp2(float x) {
#if __has_builtin(__builtin_amdgcn_exp2f)
  return __builtin_amdgcn_exp2f(x);      // v_exp_f32: 2^x
#else
  return __expf(x * 0.69314718055994530942f);
#endif
}
__device__ __forceinline__ float fast_log2(float x) {
#if __has_builtin(__builtin_amdgcn_logf)
  return __builtin_amdgcn_logf(x);       // v_log_f32: log2(x)
#else
  return __logf(x) * 1.44269504088896340736f;
#endif
}

__global__ __launch_bounds__(256)
void sdtw_kernel(const float* __restrict__ input,
                 const float* __restrict__ target,
                 float* __restrict__ out) {
  const int b = blockIdx.x;
  const int t = threadIdx.x;
  const int w = t >> 6;        // wave id 0..3
  const int lane = t & 63;

  __shared__ float dxp[2][256];   // dx[j] parity-split: dxp[j&1][j>>1]
  __shared__ float mb[4][1032];   // mailbox: mb[w][d] = boundary row value at diag d
  __shared__ int flagz[4];        // chunks completed by wave w

  const float* __restrict__ inp = input + b * 512;
  const float* __restrict__ tgt = target + b * 512;

  // stage dx[j] = inp[j] - inp[j-1], j = 1..511 (parity-split for stride-1 reads)
  for (int j = t; j < 512; j += 256) {
    float v = (j >= 1) ? inp[j] - inp[j - 1] : 0.0f;
    dxp[j & 1][j >> 1] = v;
  }
  // wave 0's virtual producer: all INF; other mailboxes need diag 0,1 = INF
  for (int k = t; k < 1032; k += 256) mb[0][k] = INF_F;
  if (t < 3) { mb[t + 1][0] = INF_F; mb[t + 1][1] = INF_F; }
  if (t < 4) flagz[t] = 0;

  const int rlo = 2 * t;        // DP row i of low cell (0..510); row 0 = boundary
  const int rhi = 2 * t + 1;    // DP row i of high cell (1..511)
  float dy_lo = (rlo >= 1) ? tgt[rlo] - tgt[rlo - 1] : 0.0f;
  float dy_hi = tgt[rhi] - tgt[rhi - 1];

  // r2 = diag d-2 values, r1 = diag d-1 values (start: d=2)
  float r2_lo = (t == 0) ? 0.0f : INF_F;   // R[0][0] = 0
  float r2_hi = INF_F;
  float r1_lo = INF_F;
  float r1_hi = INF_F;

  __syncthreads();   // staging visible; only barrier in the kernel

  const float Ce = 144.269504088896f;   // log2(e)/gamma  (gamma = 0.01)
  const float Cl = 0.00693147180560f;   // gamma*ln(2)
  float ans = 0.0f;
  int d = 2;

  for (int c = 0; c < NCHUNK; ++c) {
    if (w > 0) {
      // wait until wave w-1 finished its chunk c (mailbox filled thru d=2+cK+K-1)
      while (__hip_atomic_load(&flagz[w - 1], __ATOMIC_ACQUIRE,
                               __HIP_MEMORY_SCOPE_WORKGROUP) <= c) {
        __builtin_amdgcn_s_sleep(1);
      }
    }
#pragma unroll
    for (int k = 0; k < KCH; ++k, ++d) {
      // neighbor (row 2t-1 = lane t-1's high row) values at d-1, d-2
      float sh_r1 = __shfl_up(r1_hi, 1);
      float sh_r2 = __shfl_up(r2_hi, 1);
      float mba = mb[w][d - 2];
      float mbc = mb[w][d - 1];
      float a_lo = (lane == 0) ? mba : sh_r2;   // R[i-1][j-1]
      float c_lo = (lane == 0) ? mbc : sh_r1;   // R[i-1][j]

      // ---- low cell: (i=rlo, j=d-rlo), e-dep = r1_lo ----
      float nv_lo;
      {
        const int j = d - rlo;
        float m   = fminf(fminf(a_lo, c_lo), r1_lo);
        float mid = __builtin_amdgcn_fmed3f(a_lo, c_lo, r1_lo);
        float M   = fmaxf(fmaxf(a_lo, c_lo), r1_lo);
        float s = 1.0f + fast_exp2((m - mid) * Ce) + fast_exp2((m - M) * Ce);
        float smin = fmaf(-Cl, fast_log2(s), m);
        int jc = min(max(j, 1), 511);
        float diff = dy_lo - dxp[jc & 1][jc >> 1];
        float v = fmaf(diff, diff, smin);
        bool ok = (rlo >= 1) & (j >= 1) & (j <= 511);
        nv_lo = ok ? v : INF_F;
      }
      // ---- high cell: (i=rhi, j=d-rhi), a=r2_lo, c=r1_lo, e=r1_hi ----
      float nv_hi;
      {
        const int j = d - rhi;
        float m   = fminf(fminf(r2_lo, r1_lo), r1_hi);
        float mid = __builtin_amdgcn_fmed3f(r2_lo, r1_lo, r1_hi);
        float M   = fmaxf(fmaxf(r2_lo, r1_lo), r1_hi);
        float s = 1.0f + fast_exp2((m - mid) * Ce) + fast_exp2((m - M) * Ce);
        float smin = fmaf(-Cl, fast_log2(s), m);
        int jc = min(max(j, 1), 511);
        float diff = dy_hi - dxp[jc & 1][jc >> 1];
        float v = fmaf(diff, diff, smin);
        bool ok = (j >= 1) & (j <= 511);
        nv_hi = ok ? v : INF_F;
      }

      if (w < 3 && lane == 63) mb[w + 1][d] = nv_hi;  // publish boundary row
      if (d == DMAX) ans = nv_hi;                      // R[511][511]
      r2_lo = r1_lo; r2_hi = r1_hi; r1_lo = nv_lo; r1_hi = nv_hi;
    }
    if (w < 3) {
      __hip_atomic_store(&flagz[w], c + 1, __ATOMIC_RELEASE,
                         __HIP_MEMORY_SCOPE_WORKGROUP);
    }
  }

  if (w == 3 && lane == 63) atomicAdd(out, ans * (1.0f / 64.0f));
}

extern "C" void kernel_launch(void* const* d_in, const int* in_sizes, int n_in,
                              void* d_out, int out_size, void* d_ws, size_t ws_size,
                              hipStream_t stream) {
  const float* input  = (const float*)d_in[0];
  const float* target = (const float*)d_in[1];
  float* out = (float*)d_out;

  hipMemsetAsync(out, 0, sizeof(float), stream);
  sdtw_kernel<<<64, 256, 0, stream>>>(input, target, out);
}

// Round 3
// 201.314 us; speedup vs baseline: 1.3452x; 1.1521x over previous
//
#include <hip/hip_runtime.h>
#include <math.h>

// Soft-DTW (DILATE shape loss, alpha=1, gamma=0.01), B=64, N=512, F=1, n=511.
// One block per batch; 256 threads = 4 waves; thread t owns DP rows {2t, 2t+1}.
// Anti-diagonal wavefront in registers. Lane->lane dependency via DPP
// wave_shr1 (VALU-speed, no LDS). Wave->wave dependency via an LDS mailbox,
// chunk-pipelined (KCH diagonals) with acquire/release LDS flags; mailbox
// values preloaded per chunk with ds_read_b128 so no DS op sits on the
// per-diagonal critical chain. No __syncthreads in the main loop.

#define INF_F 1000000000.0f
#define KCH 16
#define NCHUNK 64      // 64*16 = 1024 iterations covering d = 2..1025 (>=1022)
#define DMAX 1022

__device__ __forceinline__ float fast_exp2(float x) {
  return __builtin_amdgcn_exp2f(x);      // v_exp_f32: 2^x
}
__device__ __forceinline__ float fast_log2(float x) {
  return __builtin_amdgcn_logf(x);       // v_log_f32: log2(x)
}
// whole-wave shift right by one lane: lane t gets lane t-1's value, lane 0 -> 0
__device__ __forceinline__ float dpp_wave_shr1(float x) {
  int r = __builtin_amdgcn_update_dpp(0, __float_as_int(x),
                                      0x138 /*WAVE_SHR1*/, 0xf, 0xf, true);
  return __int_as_float(r);
}

__global__ __launch_bounds__(256)
void sdtw_kernel(const float* __restrict__ input,
                 const float* __restrict__ target,
                 float* __restrict__ out) {
  const int b = blockIdx.x;
  const int t = threadIdx.x;
  const int w = t >> 6;        // wave id 0..3
  const int lane = t & 63;

  __shared__ float dxp[2][256];                 // dx[j] parity-split
  __shared__ __align__(16) float M[4][1040];    // M[w][d] = boundary value at diag d
  __shared__ int flagz[4];

  const float* __restrict__ inp = input + b * 512;
  const float* __restrict__ tgt = target + b * 512;

  // stage dx[j] = inp[j] - inp[j-1], j=1..511 (parity split => stride-1 reads)
  for (int j = t; j < 512; j += 256) {
    float v = (j >= 1) ? inp[j] - inp[j - 1] : 0.0f;
    dxp[j & 1][j >> 1] = v;
  }
  // INF-fill all mailboxes (wave 0's virtual producer stays INF forever)
  {
    float* Mf = &M[0][0];
    for (int k = t; k < 4 * 1040; k += 256) Mf[k] = INF_F;
  }
  if (t < 4) flagz[t] = 0;

  const int rlo = 2 * t;        // row of low cell (0..510); row 0 = boundary
  const int rhi = 2 * t + 1;    // row of high cell (1..511)
  float dy_lo = (rlo >= 1) ? tgt[rlo] - tgt[rlo - 1] : 0.0f;
  float dy_hi = tgt[rhi] - tgt[rhi - 1];

  // r2 = diag d-2, r1 = diag d-1 (start: d=2)
  float r2_lo = (t == 0) ? 0.0f : INF_F;   // R[0][0] = 0
  float r2_hi = INF_F;
  float r1_lo = INF_F;
  float r1_hi = INF_F;
  float shp = INF_F;            // neighbor hi at diag d-2

  __syncthreads();   // staging visible; only barrier in the kernel

  const float Ce = 144.269504088896f;   // log2(e)/gamma  (gamma = 0.01)
  const float Cl = 0.00693147180560f;   // gamma*ln(2)
  float ans = 0.0f;
  int d = 2;

  for (int c = 0; c < NCHUNK; ++c) {
    if (w > 0) {
      while (__hip_atomic_load(&flagz[w - 1], __ATOMIC_ACQUIRE,
                               __HIP_MEMORY_SCOPE_WORKGROUP) <= c) {
        __builtin_amdgcn_s_sleep(1);
      }
    }
    // preload the chunk's mailbox window M[w][16c .. 16c+19] (broadcast reads)
    const float4* Mr = (const float4*)(&M[w][16 * c]);
    float4 q0 = Mr[0], q1 = Mr[1], q2 = Mr[2], q3 = Mr[3], q4 = Mr[4];
    const float mv[20] = {q0.x, q0.y, q0.z, q0.w, q1.x, q1.y, q1.z, q1.w,
                          q2.x, q2.y, q2.z, q2.w, q3.x, q3.y, q3.z, q3.w,
                          q4.x, q4.y, q4.z, q4.w};
#pragma unroll
    for (int k = 0; k < KCH; ++k, ++d) {
      // neighbor (row 2t-1) values: hi(d-1) via DPP, hi(d-2) carried from prev iter
      float sh1 = dpp_wave_shr1(r1_hi);
      float a_lo = (lane == 0) ? mv[k] : shp;       // R[i-1][j-1] (diag d-2)
      float c_lo = (lane == 0) ? mv[k + 1] : sh1;   // R[i-1][j]   (diag d-1)

      // ---- low cell (i=rlo, j=d-rlo): softmin(a_lo, c_lo, r1_lo) ----
      float nv_lo;
      {
        const int j = d - rlo;
        float m   = fminf(fminf(a_lo, c_lo), r1_lo);
        float mid = __builtin_amdgcn_fmed3f(a_lo, c_lo, r1_lo);
        float Mx  = fmaxf(fmaxf(a_lo, c_lo), r1_lo);
        float s = 1.0f + fast_exp2((m - mid) * Ce) + fast_exp2((m - Mx) * Ce);
        float smin = fmaf(-Cl, fast_log2(s), m);
        int jc = min(max(j, 1), 511);
        float diff = dy_lo - dxp[jc & 1][jc >> 1];
        float v = fmaf(diff, diff, smin);
        bool ok = (rlo >= 1) & (j >= 1) & (j <= 511);
        nv_lo = ok ? v : INF_F;
      }
      // ---- high cell (i=rhi, j=d-rhi): softmin(r2_lo, r1_lo, r1_hi) ----
      float nv_hi;
      {
        const int j = d - rhi;
        float m   = fminf(fminf(r2_lo, r1_lo), r1_hi);
        float mid = __builtin_amdgcn_fmed3f(r2_lo, r1_lo, r1_hi);
        float Mx  = fmaxf(fmaxf(r2_lo, r1_lo), r1_hi);
        float s = 1.0f + fast_exp2((m - mid) * Ce) + fast_exp2((m - Mx) * Ce);
        float smin = fmaf(-Cl, fast_log2(s), m);
        int jc = min(max(j, 1), 511);
        float diff = dy_hi - dxp[jc & 1][jc >> 1];
        float v = fmaf(diff, diff, smin);
        bool ok = (j >= 1) & (j <= 511);
        nv_hi = ok ? v : INF_F;
      }

      if (w < 3 && lane == 63) M[w + 1][d] = nv_hi;   // publish boundary row
      if (d == DMAX) ans = nv_hi;                     // R[511][511]
      shp = sh1;
      r2_lo = r1_lo; r2_hi = r1_hi; r1_lo = nv_lo; r1_hi = nv_hi;
    }
    if (w < 3) {
      __hip_atomic_store(&flagz[w], c + 1, __ATOMIC_RELEASE,
                         __HIP_MEMORY_SCOPE_WORKGROUP);
    }
  }

  if (w == 3 && lane == 63) atomicAdd(out, ans * (1.0f / 64.0f));
}

extern "C" void kernel_launch(void* const* d_in, const int* in_sizes, int n_in,
                              void* d_out, int out_size, void* d_ws, size_t ws_size,
                              hipStream_t stream) {
  const float* input  = (const float*)d_in[0];
  const float* target = (const float*)d_in[1];
  float* out = (float*)d_out;

  hipMemsetAsync(out, 0, sizeof(float), stream);
  sdtw_kernel<<<64, 256, 0, stream>>>(input, target, out);
}

// Round 4
// 155.044 us; speedup vs baseline: 1.7467x; 1.2984x over previous
//
#include <hip/hip_runtime.h>
#include <math.h>

// Soft-DTW (DILATE shape loss, alpha=1, gamma=0.01), B=64, N=512, F=1, n=511.
// One block/batch; 256 threads = 4 waves; thread t owns DP rows {2t, 2t+1}.
// Scaled domain: all R values carry factor Ce = log2(e)/gamma, so softmin is
//   smin' = m' - log2(1 + 2^(m'-mid') + 2^(m'-max'))
// Inner 16-step body is pure VALU: dx & mailbox windows preloaded into named
// registers (pinned with empty asm), dx double-buffered across chunks.
// Lane->lane dep via DPP wave_shr1; wave->wave via LDS mailbox + flags.

#define CE_F   144.26950408889635f      // log2(e)/gamma
#define INF_S  1.4426950408889634e11f   // 1e9 * Ce

typedef float v4f __attribute__((ext_vector_type(4)));

__device__ __forceinline__ float fexp2(float x){ return __builtin_amdgcn_exp2f(x); }
__device__ __forceinline__ float flog2(float x){ return __builtin_amdgcn_logf(x); }
__device__ __forceinline__ float dpp_shr1(float x){
  int r = __builtin_amdgcn_update_dpp(0, __float_as_int(x), 0x138 /*WAVE_SHR1*/,
                                      0xf, 0xf, true);
  return __int_as_float(r);
}
#define PINF(v) asm volatile("" : "+v"(v))
#define PIN4(v) asm volatile("" : "+v"(v))

#define LOADX(P, B) { const int _b = (B); \
  P##0  = dxe[_b];     P##1  = dxe[_b+1];  P##2  = dxe[_b+2];  P##3  = dxe[_b+3]; \
  P##4  = dxe[_b+4];   P##5  = dxe[_b+5];  P##6  = dxe[_b+6];  P##7  = dxe[_b+7]; \
  P##8  = dxe[_b+8];   P##9  = dxe[_b+9];  P##10 = dxe[_b+10]; P##11 = dxe[_b+11]; \
  P##12 = dxe[_b+12];  P##13 = dxe[_b+13]; P##14 = dxe[_b+14]; P##15 = dxe[_b+15]; \
  P##16 = dxe[_b+16]; }

#define PINX(P) { PINF(P##0); PINF(P##1); PINF(P##2); PINF(P##3); PINF(P##4); \
  PINF(P##5); PINF(P##6); PINF(P##7); PINF(P##8); PINF(P##9); PINF(P##10); \
  PINF(P##11); PINF(P##12); PINF(P##13); PINF(P##14); PINF(P##15); PINF(P##16); }

// One diagonal: K compile-time 0..15. MA=boundary(d-2), MB=boundary(d-1),
// XA=dx[j_hi], XB=dx[j_lo]. Updates SH,R2L,R1L,R1H; stores pb##K.
#define STEP(K, MA, MB, XA, XB) { \
  float sh1 = dpp_shr1(R1H); \
  float aL = lane0 ? (MA) : SH; \
  float cL = lane0 ? (MB) : sh1; \
  float mL = fminf(fminf(aL, cL), R1L); \
  float dL = __builtin_amdgcn_fmed3f(aL, cL, R1L); \
  float ML = fmaxf(fmaxf(aL, cL), R1L); \
  float sL = 1.0f + fexp2(mL - dL) + fexp2(mL - ML); \
  float vL = mL - flog2(sL); \
  float uL = dy_lo - (XB); \
  vL = fmaf(uL * CE_F, uL, vL); \
  unsigned jkL = (unsigned)(jbL + (K)); \
  float nvL = (jkL <= 510u) ? vL : INF_S; \
  float mH = fminf(fminf(R2L, R1L), R1H); \
  float dH = __builtin_amdgcn_fmed3f(R2L, R1L, R1H); \
  float MH = fmaxf(fmaxf(R2L, R1L), R1H); \
  float sH = 1.0f + fexp2(mH - dH) + fexp2(mH - MH); \
  float vH = mH - flog2(sH); \
  float uH = dy_hi - (XA); \
  vH = fmaf(uH * CE_F, uH, vH); \
  unsigned jkH = (unsigned)(jbH + (K)); \
  float nvH = (jkH <= 510u) ? vH : INF_S; \
  pb##K = nvH; \
  if ((K) == 12) { if (cc == 63) ans = nvH; } \
  SH = sh1; R2L = R1L; R1L = nvL; R1H = nvH; }

#define CHUNK(C, XU, XP) { \
  const int cc = (C); \
  if (w > 0) { \
    while (__hip_atomic_load(&flagz[w-1], __ATOMIC_ACQUIRE, \
                             __HIP_MEMORY_SCOPE_WORKGROUP) <= cc) {} \
    const v4f* Mr = (const v4f*)&Mbx[w][16*cc]; \
    q0 = Mr[0]; q1 = Mr[1]; q2 = Mr[2]; q3 = Mr[3]; m16v = Mbx[w][16*cc+16]; \
    PIN4(q0); PIN4(q1); PIN4(q2); PIN4(q3); PINF(m16v); \
  } \
  PINX(XU); \
  LOADX(XP, dxb + 16*(cc+1)); \
  asm volatile("" ::: "memory"); \
  const int jbL = jbL0 + 16*cc; \
  const int jbH = jbH0 + 16*cc; \
  STEP(0,  q0.x, q0.y, XU##0,  XU##1 ) \
  STEP(1,  q0.y, q0.z, XU##1,  XU##2 ) \
  STEP(2,  q0.z, q0.w, XU##2,  XU##3 ) \
  STEP(3,  q0.w, q1.x, XU##3,  XU##4 ) \
  STEP(4,  q1.x, q1.y, XU##4,  XU##5 ) \
  STEP(5,  q1.y, q1.z, XU##5,  XU##6 ) \
  STEP(6,  q1.z, q1.w, XU##6,  XU##7 ) \
  STEP(7,  q1.w, q2.x, XU##7,  XU##8 ) \
  STEP(8,  q2.x, q2.y, XU##8,  XU##9 ) \
  STEP(9,  q2.y, q2.z, XU##9,  XU##10) \
  STEP(10, q2.z, q2.w, XU##10, XU##11) \
  STEP(11, q2.w, q3.x, XU##11, XU##12) \
  STEP(12, q3.x, q3.y, XU##12, XU##13) \
  STEP(13, q3.y, q3.z, XU##13, XU##14) \
  STEP(14, q3.z, q3.w, XU##14, XU##15) \
  STEP(15, q3.w, m16v, XU##15, XU##16) \
  if (w < 3) { \
    if (lane == 63) { \
      float2* Pd = (float2*)&Mbx[w+1][16*cc+2]; \
      Pd[0] = make_float2(pb0,  pb1);  Pd[1] = make_float2(pb2,  pb3); \
      Pd[2] = make_float2(pb4,  pb5);  Pd[3] = make_float2(pb6,  pb7); \
      Pd[4] = make_float2(pb8,  pb9);  Pd[5] = make_float2(pb10, pb11); \
      Pd[6] = make_float2(pb12, pb13); Pd[7] = make_float2(pb14, pb15); \
    } \
    __hip_atomic_store(&flagz[w], cc+1, __ATOMIC_RELEASE, \
                       __HIP_MEMORY_SCOPE_WORKGROUP); \
  } }

__global__ __launch_bounds__(256)
void sdtw_kernel(const float* __restrict__ input,
                 const float* __restrict__ target,
                 float* __restrict__ out) {
  const int b = blockIdx.x;
  const int t = threadIdx.x;
  const int w = t >> 6;
  const int lane = t & 63;
  const bool lane0 = (lane == 0);

  __shared__ float dxe[1568];                 // dx[j] at dxe[512+j]; zero pad
  __shared__ __align__(16) float Mbx[4][1040]; // Mbx[w][d] = boundary diag d (scaled)
  __shared__ int flagz[4];

  const float* __restrict__ inp = input + b * 512;
  const float* __restrict__ tgt = target + b * 512;

  for (int idx = t; idx < 1568; idx += 256) {
    float v = 0.0f;
    if (idx >= 513 && idx <= 1023) v = inp[idx - 512] - inp[idx - 513];
    dxe[idx] = v;
  }
  for (int k2 = t; k2 < 4 * 1040; k2 += 256) (&Mbx[0][0])[k2] = INF_S;
  if (t < 4) flagz[t] = 0;

  float dy_lo = (t >= 1) ? (tgt[2*t] - tgt[2*t - 1]) : 0.0f;
  float dy_hi = tgt[2*t + 1] - tgt[2*t];

  float SH  = INF_S;
  float R2L = (t == 0) ? 0.0f : INF_S;   // R'[0][0] = 0
  float R1L = INF_S, R1H = INF_S;
  v4f q0 = {INF_S, INF_S, INF_S, INF_S};
  v4f q1 = q0, q2 = q0, q3 = q0;
  float m16v = INF_S;
  float pb0, pb1, pb2, pb3, pb4, pb5, pb6, pb7;
  float pb8, pb9, pb10, pb11, pb12, pb13, pb14, pb15;
  float xa0, xa1, xa2, xa3, xa4, xa5, xa6, xa7, xa8;
  float xa9, xa10, xa11, xa12, xa13, xa14, xa15, xa16;
  float xb0, xb1, xb2, xb3, xb4, xb5, xb6, xb7, xb8;
  float xb9, xb10, xb11, xb12, xb13, xb14, xb15, xb16;

  const int dxb  = 513 - 2 * t;                       // dxe index of dx[j_hi] at chunk0 K=0
  const int jbL0 = 1 - 2 * t + ((t == 0) ? (1 << 30) : 0);
  const int jbH0 = -2 * t;
  float ans = 0.0f;

  __syncthreads();

  LOADX(xa, dxb);   // chunk 0 window

#pragma unroll 1
  for (int c = 0; c < 64; c += 2) {
    CHUNK(c,     xa, xb)
    CHUNK(c + 1, xb, xa)
  }

  if (w == 3 && lane == 63) {
    atomicAdd(out, ans * (float)(1.0 / (144.26950408889635 * 64.0)));
  }
}

extern "C" void kernel_launch(void* const* d_in, const int* in_sizes, int n_in,
                              void* d_out, int out_size, void* d_ws, size_t ws_size,
                              hipStream_t stream) {
  const float* input  = (const float*)d_in[0];
  const float* target = (const float*)d_in[1];
  float* out = (float*)d_out;

  hipMemsetAsync(out, 0, sizeof(float), stream);
  sdtw_kernel<<<64, 256, 0, stream>>>(input, target, out);
}

// Round 5
// 152.605 us; speedup vs baseline: 1.7746x; 1.0160x over previous
//
#include <hip/hip_runtime.h>
#include <math.h>

// Soft-DTW (DILATE shape loss, alpha=1, gamma=0.01), B=64, N=512, F=1, n=511.
// One block/batch; 512 threads = 8 waves; thread t owns DP row t (row 0 is the
// boundary row, always INF -> uniform code). Scaled log2 domain (R' = R*Ce):
//   smin' = m' - log2(1 + 2^(m'-mid') + 2^(m'-max'))
// Pure-VALU 16-step chunks: dx window (stride-1, conflict-free) and mailbox
// window preloaded into pinned registers; dx double-buffered across chunks.
// Lane->lane dep via one DPP wave_shr1/step (d-2 value carried); wave->wave
// dep via LDS mailbox + acquire/release flags. 2 waves/SIMD so the two
// recurrence chains interleave and hide each other's latency.

#define CE_F   144.26950408889635f      // log2(e)/gamma
#define INF_S  1.4426950408889634e11f   // 1e9 * Ce

typedef float v4f __attribute__((ext_vector_type(4)));

__device__ __forceinline__ float fexp2(float x){ return __builtin_amdgcn_exp2f(x); }
__device__ __forceinline__ float flog2(float x){ return __builtin_amdgcn_logf(x); }
__device__ __forceinline__ float dpp_shr1(float x){
  int r = __builtin_amdgcn_update_dpp(0, __float_as_int(x), 0x138 /*WAVE_SHR1*/,
                                      0xf, 0xf, true);
  return __int_as_float(r);
}
#define PINF(v) asm volatile("" : "+v"(v))

#define LOADX(P, B) { const int _b = (B); \
  P##0  = dxe[_b];     P##1  = dxe[_b+1];  P##2  = dxe[_b+2];  P##3  = dxe[_b+3]; \
  P##4  = dxe[_b+4];   P##5  = dxe[_b+5];  P##6  = dxe[_b+6];  P##7  = dxe[_b+7]; \
  P##8  = dxe[_b+8];   P##9  = dxe[_b+9];  P##10 = dxe[_b+10]; P##11 = dxe[_b+11]; \
  P##12 = dxe[_b+12];  P##13 = dxe[_b+13]; P##14 = dxe[_b+14]; P##15 = dxe[_b+15]; }

#define PINX(P) { PINF(P##0); PINF(P##1); PINF(P##2); PINF(P##3); PINF(P##4); \
  PINF(P##5); PINF(P##6); PINF(P##7); PINF(P##8); PINF(P##9); PINF(P##10); \
  PINF(P##11); PINF(P##12); PINF(P##13); PINF(P##14); PINF(P##15); }

// One diagonal step for the single cell (row t, j = d - t).
// MA = boundary value at diag d-2, MB = at d-1 (used by lane 0 only).
#define STEP(K, MA, MB, XW) { \
  float sh1 = dpp_shr1(r1); \
  float a_  = lane0 ? (MA) : SH; \
  float c_  = lane0 ? (MB) : sh1; \
  float m_  = fminf(fminf(a_, c_), r1); \
  float d_  = __builtin_amdgcn_fmed3f(a_, c_, r1); \
  float M_  = fmaxf(fmaxf(a_, c_), r1); \
  float u_  = dy - (XW); \
  float mc  = fmaf(u_ * CE_F, u_, m_); \
  float s_  = 1.0f + fexp2(m_ - d_) + fexp2(m_ - M_); \
  float v_  = mc - flog2(s_); \
  unsigned jk = (unsigned)(jb + (K)); \
  float nv = (jk <= 510u) ? v_ : INF_S; \
  pb##K = nv; \
  if ((K) == 12) { if (cc == 63) ans = nv; } \
  SH = sh1; r1 = nv; }

#define CHUNK(C, XU, XP) { \
  const int cc = (C); \
  if (w > 0) { \
    while (__hip_atomic_load(&flagz[w-1], __ATOMIC_ACQUIRE, \
                             __HIP_MEMORY_SCOPE_WORKGROUP) <= cc) {} \
    const v4f* Mr = (const v4f*)&Mbx[w][16*cc]; \
    q0 = Mr[0]; q1 = Mr[1]; q2 = Mr[2]; q3 = Mr[3]; m16v = Mbx[w][16*cc+16]; \
    PINF(q0); PINF(q1); PINF(q2); PINF(q3); PINF(m16v); \
  } \
  PINX(XU); \
  LOADX(XP, dxb + 16*(cc+1)); \
  asm volatile("" ::: "memory"); \
  const int jb = jbase + 16*cc; \
  STEP(0,  q0.x, q0.y, XU##0 ) \
  STEP(1,  q0.y, q0.z, XU##1 ) \
  STEP(2,  q0.z, q0.w, XU##2 ) \
  STEP(3,  q0.w, q1.x, XU##3 ) \
  STEP(4,  q1.x, q1.y, XU##4 ) \
  STEP(5,  q1.y, q1.z, XU##5 ) \
  STEP(6,  q1.z, q1.w, XU##6 ) \
  STEP(7,  q1.w, q2.x, XU##7 ) \
  STEP(8,  q2.x, q2.y, XU##8 ) \
  STEP(9,  q2.y, q2.z, XU##9 ) \
  STEP(10, q2.z, q2.w, XU##10) \
  STEP(11, q2.w, q3.x, XU##11) \
  STEP(12, q3.x, q3.y, XU##12) \
  STEP(13, q3.y, q3.z, XU##13) \
  STEP(14, q3.z, q3.w, XU##14) \
  STEP(15, q3.w, m16v, XU##15) \
  if (w < 7) { \
    if (lane == 63) { \
      float2* Pd = (float2*)&Mbx[w+1][16*cc+2]; \
      Pd[0] = make_float2(pb0,  pb1);  Pd[1] = make_float2(pb2,  pb3); \
      Pd[2] = make_float2(pb4,  pb5);  Pd[3] = make_float2(pb6,  pb7); \
      Pd[4] = make_float2(pb8,  pb9);  Pd[5] = make_float2(pb10, pb11); \
      Pd[6] = make_float2(pb12, pb13); Pd[7] = make_float2(pb14, pb15); \
    } \
    __hip_atomic_store(&flagz[w], cc+1, __ATOMIC_RELEASE, \
                       __HIP_MEMORY_SCOPE_WORKGROUP); \
  } }

__global__ __launch_bounds__(512)
void sdtw_kernel(const float* __restrict__ input,
                 const float* __restrict__ target,
                 float* __restrict__ out) {
  const int b = blockIdx.x;
  const int t = threadIdx.x;
  const int w = t >> 6;
  const int lane = t & 63;
  const bool lane0 = (lane == 0);

  __shared__ float dxe[1560];                  // dx[j] at dxe[512+j]; zero pad
  __shared__ __align__(16) float Mbx[8][1040]; // Mbx[w][d] = boundary diag d
  __shared__ int flagz[8];

  const float* __restrict__ inp = input + b * 512;
  const float* __restrict__ tgt = target + b * 512;

  for (int idx = t; idx < 1560; idx += 512) {
    float v = 0.0f;
    if (idx >= 513 && idx <= 1023) v = inp[idx - 512] - inp[idx - 513];
    dxe[idx] = v;
  }
  for (int k2 = t; k2 < 8 * 1040; k2 += 512) (&Mbx[0][0])[k2] = INF_S;
  if (t < 8) flagz[t] = 0;

  float dy = (t >= 1) ? (tgt[t] - tgt[t - 1]) : 0.0f;   // dy[t-1] for row t

  float r1 = INF_S;                        // own value at diag d-1
  float r2 = (t == 0) ? 0.0f : INF_S;      // own value at diag d-2 (R'[0][0]=0)
  v4f q0 = {INF_S, INF_S, INF_S, INF_S};
  v4f q1 = q0, q2 = q0, q3 = q0;
  float m16v = INF_S;
  float pb0, pb1, pb2, pb3, pb4, pb5, pb6, pb7;
  float pb8, pb9, pb10, pb11, pb12, pb13, pb14, pb15;
  float xa0, xa1, xa2, xa3, xa4, xa5, xa6, xa7;
  float xa8, xa9, xa10, xa11, xa12, xa13, xa14, xa15;
  float xb0, xb1, xb2, xb3, xb4, xb5, xb6, xb7;
  float xb8, xb9, xb10, xb11, xb12, xb13, xb14, xb15;

  const int dxb   = 514 - t;               // dxe index of dx[j] at chunk0,K=0
  const int jbase = 1 - t + ((t == 0) ? (1 << 30) : 0);  // jb+K = j-1
  float ans = 0.0f;

  __syncthreads();

  float SH = dpp_shr1(r2);   // neighbor's value at diag d-2 (seeds R'[0][0]=0)
  LOADX(xa, dxb);            // chunk 0 dx window

#pragma unroll 1
  for (int c = 0; c < 64; c += 2) {
    CHUNK(c,     xa, xb)
    CHUNK(c + 1, xb, xa)
  }

  if (w == 7 && lane == 63) {
    atomicAdd(out, ans * (float)(1.0 / (144.26950408889635 * 64.0)));
  }
}

extern "C" void kernel_launch(void* const* d_in, const int* in_sizes, int n_in,
                              void* d_out, int out_size, void* d_ws, size_t ws_size,
                              hipStream_t stream) {
  const float* input  = (const float*)d_in[0];
  const float* target = (const float*)d_in[1];
  float* out = (float*)d_out;

  hipMemsetAsync(out, 0, sizeof(float), stream);
  sdtw_kernel<<<64, 512, 0, stream>>>(input, target, out);
}